// Round 1
// baseline (809.940 us; speedup 1.0000x reference)
//
#include <hip/hip_runtime.h>
#include <math.h>

#define N512 512
#define BM 64
#define BN 64
#define BK 16

// M[n,k] = s_k * cos(pi * k * (2n+1) / (2N)), s_0=1/sqrt(N), s_k=sqrt(2/N)
// Angle reduced exactly mod 4N in integers so cosf sees [0, 2*pi).
__global__ __launch_bounds__(256) void build_idct_matrix(float* __restrict__ M) {
    int idx = blockIdx.x * 256 + threadIdx.x;          // 0 .. 512*512-1
    int n = idx >> 9;
    int k = idx & 511;
    int j = (k * (2 * n + 1)) & (4 * N512 - 1);        // mod 2048 (4N is pow2)
    float theta = (float)j * (3.14159265358979323846f / (2.0f * (float)N512));
    float s = (k == 0) ? 0.044194173824159216f         // 1/sqrt(512)
                       : 0.0625f;                      // sqrt(2/512) = 1/16
    M[idx] = s * cosf(theta);
}

// Stage 1: C[r, n] = sum_k A[r, k] * M[n, k]
// A: [rows x 512] row-major (rows = chunk*512 image rows), M: [512 x 512], C: [rows x 512]
__global__ __launch_bounds__(256) void idct_s1(const float* __restrict__ A,
                                               const float* __restrict__ M,
                                               float* __restrict__ C) {
    __shared__ __align__(16) float As[BK][BM + 4];
    __shared__ __align__(16) float Bs[BK][BN + 4];
    const int t  = threadIdx.x;
    const int n0 = blockIdx.x * BN;
    const long r0 = (long)blockIdx.y * BM;
    const int tk = t & 15;          // k within tile (coalesced inner dim)
    const int tr = t >> 4;          // 0..15 row group
    const int tx = t & 15;          // n micro-tile group for compute
    const int ty = t >> 4;          // m micro-tile group for compute
    float acc[4][4] = {};
    for (int k0 = 0; k0 < N512; k0 += BK) {
#pragma unroll
        for (int i = 0; i < 4; ++i)
            As[tk][tr + 16 * i] = A[(r0 + tr + 16 * i) * N512 + (k0 + tk)];
#pragma unroll
        for (int i = 0; i < 4; ++i)
            Bs[tk][tr + 16 * i] = M[(long)(n0 + tr + 16 * i) * N512 + (k0 + tk)];
        __syncthreads();
#pragma unroll
        for (int k = 0; k < BK; ++k) {
            float4 av = *(const float4*)&As[k][ty * 4];
            float4 bv = *(const float4*)&Bs[k][tx * 4];
            float a[4] = {av.x, av.y, av.z, av.w};
            float b[4] = {bv.x, bv.y, bv.z, bv.w};
#pragma unroll
            for (int i = 0; i < 4; ++i)
#pragma unroll
                for (int j = 0; j < 4; ++j)
                    acc[i][j] += a[i] * b[j];
        }
        __syncthreads();
    }
#pragma unroll
    for (int i = 0; i < 4; ++i) {
        float4 v = make_float4(acc[i][0], acc[i][1], acc[i][2], acc[i][3]);
        *(float4*)&C[(r0 + ty * 4 + i) * N512 + (n0 + tx * 4)] = v;
    }
}

// Stage 2: Out[bc][m, n] = sum_h M[m, h] * T[bc][h, n]
__global__ __launch_bounds__(256) void idct_s2(const float* __restrict__ M,
                                               const float* __restrict__ T,
                                               float* __restrict__ Out) {
    __shared__ __align__(16) float As[BK][BM + 4];
    __shared__ __align__(16) float Bs[BK][BN + 4];
    const int t  = threadIdx.x;
    const int n0 = blockIdx.x * BN;
    const int m0 = blockIdx.y * BM;
    const long slice = (long)blockIdx.z * N512 * N512;
    const float* Bsl = T + slice;
    float* C = Out + slice;
    const int tx = t & 15;
    const int ty = t >> 4;
    float acc[4][4] = {};
    for (int k0 = 0; k0 < N512; k0 += BK) {
        // A tile: M[m0+ty+16i][k0+tx]  (row-major, coalesced over tx)
#pragma unroll
        for (int i = 0; i < 4; ++i)
            As[tx][ty + 16 * i] = M[(long)(m0 + ty + 16 * i) * N512 + (k0 + tx)];
        // B tile: T[k0+h][n0+n], h=(t>>6)+4i, n=t&63 (fully coalesced rows)
#pragma unroll
        for (int i = 0; i < 4; ++i)
            Bs[(t >> 6) + 4 * i][t & 63] =
                Bsl[(long)(k0 + (t >> 6) + 4 * i) * N512 + (n0 + (t & 63))];
        __syncthreads();
#pragma unroll
        for (int k = 0; k < BK; ++k) {
            float4 av = *(const float4*)&As[k][ty * 4];
            float4 bv = *(const float4*)&Bs[k][tx * 4];
            float a[4] = {av.x, av.y, av.z, av.w};
            float b[4] = {bv.x, bv.y, bv.z, bv.w};
#pragma unroll
            for (int i = 0; i < 4; ++i)
#pragma unroll
                for (int j = 0; j < 4; ++j)
                    acc[i][j] += a[i] * b[j];
        }
        __syncthreads();
    }
#pragma unroll
    for (int i = 0; i < 4; ++i) {
        float4 v = make_float4(acc[i][0], acc[i][1], acc[i][2], acc[i][3]);
        *(float4*)&C[(long)(m0 + ty * 4 + i) * N512 + (n0 + tx * 4)] = v;
    }
}

extern "C" void kernel_launch(void* const* d_in, const int* in_sizes, int n_in,
                              void* d_out, int out_size, void* d_ws, size_t ws_size,
                              hipStream_t stream) {
    const float* X = (const float*)d_in[0];
    float* out = (float*)d_out;

    const long plane = (long)N512 * N512;              // 262144
    const int slices = in_sizes[0] / (int)plane;       // B*C = 96

    float* M = (float*)d_ws;                           // 1 MB
    float* T = M + plane;                              // intermediate

    // Adaptive chunking over slices in case ws is small.
    long avail_floats = (long)(ws_size / 4) - plane;
    int chunk = (avail_floats > 0) ? (int)(avail_floats / plane) : 1;
    if (chunk > slices) chunk = slices;
    if (chunk < 1) chunk = 1;

    build_idct_matrix<<<dim3((int)(plane / 256)), dim3(256), 0, stream>>>(M);

    for (int s0 = 0; s0 < slices; s0 += chunk) {
        int c = (s0 + chunk <= slices) ? chunk : (slices - s0);
        const float* Xc = X + (long)s0 * plane;
        float* Oc = out + (long)s0 * plane;
        int rows = c * N512;
        idct_s1<<<dim3(N512 / BN, rows / BM), dim3(256), 0, stream>>>(Xc, M, T);
        idct_s2<<<dim3(N512 / BN, N512 / BM, c), dim3(256), 0, stream>>>(M, T, Oc);
    }
}

// Round 2
// 251.909 us; speedup vs baseline: 3.2152x; 3.2152x over previous
//
#include <hip/hip_runtime.h>
#include <math.h>
#include <stdint.h>

#define N512 512

typedef __attribute__((ext_vector_type(8))) short short8;
typedef __attribute__((ext_vector_type(4))) float floatx4;

__device__ __forceinline__ short f2bf(float f) {
    uint32_t u = __float_as_uint(f);
    uint32_t r = u + 0x7fffu + ((u >> 16) & 1u);
    return (short)(r >> 16);
}

__device__ __forceinline__ void gload_lds16(const void* g, void* l) {
    __builtin_amdgcn_global_load_lds(
        (const __attribute__((address_space(1))) void*)g,
        (__attribute__((address_space(3))) void*)l,
        16, 0, 0);
}

// M[n,k] = s_k * cos(pi * k * (2n+1) / (2N)), bf16
__global__ __launch_bounds__(256) void build_idct_matrix_bf16(short* __restrict__ M) {
    int idx = blockIdx.x * 256 + threadIdx.x;
    int n = idx >> 9;
    int k = idx & 511;
    int j = (k * (2 * n + 1)) & (4 * N512 - 1);
    float theta = (float)j * (3.14159265358979323846f / (2.0f * (float)N512));
    float s = (k == 0) ? 0.044194173824159216f : 0.0625f;
    M[idx] = f2bf(s * cosf(theta));
}

__global__ __launch_bounds__(256) void cvt_f32_bf16(const float4* __restrict__ in,
                                                    short* __restrict__ out) {
    long i = (long)blockIdx.x * 256 + threadIdx.x;
    float4 v = in[i];
    short4 o;
    o.x = f2bf(v.x); o.y = f2bf(v.y); o.z = f2bf(v.z); o.w = f2bf(v.w);
    *(short4*)&out[4 * i] = o;
}

// C[i,j] = sum_k A[i,k] * B[j,k]   (both operands K-contiguous, bf16, K=512)
// A: [512][512] (the IDCT matrix, shared). B: per-slice [512][512]. C: per-slice [512][512].
// 128x128 tile, BK=64, 4 waves (2x2), each wave 4x4 of 16x16x32 MFMA.
// LDS staged via global_load_lds(16B) with XOR swizzle on 16B groups so
// ds_read_b128 fragment reads are conflict-free.
template <typename CT>
__global__ __launch_bounds__(256) void gemm_bt(const short* __restrict__ A,
                                               const short* __restrict__ Bg,
                                               CT* __restrict__ Cg) {
    __shared__ short lds[2 * 8192];   // A tile 128x64 (16KB) then B tile (16KB)
    short* ldsA = lds;
    short* ldsB = lds + 8192;

    const int t = threadIdx.x;
    const int w = t >> 6;          // wave 0..3
    const int l = t & 63;
    const int q = (t >> 4) & 3;    // quad in wave
    const int r = t & 15;

    const int bm0 = blockIdx.y * 128;   // C rows (A rows)
    const int bn0 = blockIdx.x * 128;   // C cols (B rows)
    const int wm0 = (w >> 1) * 64;
    const int wn0 = (w & 1) * 64;

    const short* Bs = Bg + ((long)blockIdx.z << 18);
    CT* C = Cg + ((long)blockIdx.z << 18);

    // staging geometry: instr i of wave w covers rows (w*4+i)*8 .. +7 of the tile
    const int rsub = l >> 3;                 // 0..7 row within 8-row chunk
    const int glog = (l & 7) ^ rsub;         // swizzled 16B-group to fetch

    floatx4 acc[4][4] = {};

    for (int kt = 0; kt < 8; ++kt) {
        const int k0 = kt * 64;
#pragma unroll
        for (int i = 0; i < 4; ++i) {
            const int chunk = w * 4 + i;         // 0..15
            const int rt = chunk * 8 + rsub;     // tile row 0..127
            gload_lds16(A + (((long)(bm0 + rt)) << 9) + k0 + glog * 8,
                        ldsA + chunk * 512);
            gload_lds16(Bs + (((long)(bn0 + rt)) << 9) + k0 + glog * 8,
                        ldsB + chunk * 512);
        }
        __syncthreads();
#pragma unroll
        for (int kk = 0; kk < 2; ++kk) {
            const int c = kk * 4 + q;            // logical 16B group (k = c*8..c*8+7)
            const int goff = ((c ^ (r & 7)) * 8);
            short8 af[4], bf[4];
#pragma unroll
            for (int i = 0; i < 4; ++i) {
                af[i] = *(const short8*)(ldsA + (wm0 + i * 16 + r) * 64 + goff);
                bf[i] = *(const short8*)(ldsB + (wn0 + i * 16 + r) * 64 + goff);
            }
#pragma unroll
            for (int i = 0; i < 4; ++i)
#pragma unroll
                for (int j = 0; j < 4; ++j)
                    acc[i][j] = __builtin_amdgcn_mfma_f32_16x16x32_bf16(
                        af[i], bf[j], acc[i][j], 0, 0, 0);
        }
        __syncthreads();
    }

    // epilogue: D row = quad*4+reg, col = lane&15 within each 16x16 tile
#pragma unroll
    for (int i = 0; i < 4; ++i) {
        const int mrow = bm0 + wm0 + i * 16 + q * 4;
#pragma unroll
        for (int j = 0; j < 4; ++j) {
            const int ncol = bn0 + wn0 + j * 16 + r;
#pragma unroll
            for (int rg = 0; rg < 4; ++rg) {
                float v = acc[i][j][rg];
                if constexpr (sizeof(CT) == 4) {
                    C[(long)(mrow + rg) * N512 + ncol] = (CT)v;
                } else {
                    C[(long)(mrow + rg) * N512 + ncol] = (CT)f2bf(v);
                }
            }
        }
    }
}

extern "C" void kernel_launch(void* const* d_in, const int* in_sizes, int n_in,
                              void* d_out, int out_size, void* d_ws, size_t ws_size,
                              hipStream_t stream) {
    const float* X = (const float*)d_in[0];
    float* out = (float*)d_out;

    const long plane = (long)N512 * N512;          // 262144
    const int slices = in_sizes[0] / (int)plane;   // 96

    short* Mb = (short*)d_ws;                      // 512 KB
    char* rest = (char*)d_ws + plane * sizeof(short);

    // per-slice: Xb (0.5MB) + Tt (0.5MB)
    long avail = (long)ws_size - plane * 2;
    int chunk = (int)(avail / (plane * 4));        // bytes per slice pair = 4*plane
    if (chunk > slices) chunk = slices;
    if (chunk < 1) chunk = 1;

    build_idct_matrix_bf16<<<dim3((int)(plane / 256)), dim3(256), 0, stream>>>(Mb);

    for (int s0 = 0; s0 < slices; s0 += chunk) {
        int c = (s0 + chunk <= slices) ? chunk : (slices - s0);
        short* Xb = (short*)rest;                       // c * plane bf16
        short* Tt = Xb + (long)c * plane;               // c * plane bf16

        // convert chunk of X to bf16
        long n4 = (long)c * plane / 4;
        cvt_f32_bf16<<<dim3((int)(n4 / 256)), dim3(256), 0, stream>>>(
            (const float4*)(X + (long)s0 * plane), Xb);

        // stage 1: Tt[z][n][h] = sum_k M[n,k] * X[z][h,k]
        gemm_bt<short><<<dim3(4, 4, c), dim3(256), 0, stream>>>(Mb, Xb, Tt);

        // stage 2: Out[z][m][n] = sum_h M[m,h] * Tt[z][n,h]
        gemm_bt<float><<<dim3(4, 4, c), dim3(256), 0, stream>>>(
            Mb, Tt, out + (long)s0 * plane);
    }
}